// Round 1
// baseline (54.547 us; speedup 1.0000x reference)
//
#include <hip/hip_runtime.h>
#include <math.h>

#define WDET 384
#define NANG 180

// ---------------------------------------------------------------------------
// Kernel 1: exact DFT of the ramp filter, h[d] = (1/P) sum_m filt[m] cos(2pi m d / P)
// P = 1024 (pad size), filt[m] = 2*min(m, P-m)/P.  Scale pi/360 folded in.
// grid = 384 blocks (one per d), block = 256 threads (4 terms each) + tree reduce.
// ---------------------------------------------------------------------------
__global__ void k_ramp(float* __restrict__ h) {
    int d = blockIdx.x;
    int t = threadIdx.x;
    double local = 0.0;
    for (int s = 0; s < 4; ++s) {
        int m = t + 256 * s;
        int mm = (m <= 512) ? m : (1024 - m);          // min(m, 1024-m)
        double filt = (double)mm * (1.0 / 512.0);      // 2*mm/1024
        int tm = (m * d) & 1023;
        local += filt * cos(6.283185307179586 * ((double)tm * (1.0 / 1024.0)));
    }
    __shared__ double red[256];
    red[t] = local;
    __syncthreads();
    for (int off = 128; off > 0; off >>= 1) {
        if (t < off) red[t] += red[t + off];
        __syncthreads();
    }
    if (t == 0) h[d] = (float)(red[0] * (1.0 / 1024.0) * (M_PI / 360.0));
}

// ---------------------------------------------------------------------------
// Kernel 2: per-angle tables A[a] = 191.5*cos(rad), B[a] = 191.5*sin(rad),
// rad = fl32(a * fl32(pi/180)) exactly as jnp.deg2rad in f32.
// ---------------------------------------------------------------------------
__global__ void k_trig(float* __restrict__ AB) {
    int a = threadIdx.x;
    if (a < NANG) {
        float radf = (float)a * (float)(M_PI / 180.0);  // f32 constant, f32 mul
        double c = cos((double)radf);
        double s = sin((double)radf);
        AB[a]        = (float)(191.5 * c);
        AB[a + NANG] = (float)(191.5 * s);
    }
}

// ---------------------------------------------------------------------------
// Kernel 3: ramp filter as Toeplitz matmul.
// F_t[n][a][k] = sum_j h[|k-j|] * x[n,0,j,a]   (h is even: h[(k-j) mod 1024] = h[|k-j|])
// grid = (180 angles, 2 batch), block = 384 threads (k).
// ---------------------------------------------------------------------------
__global__ void k_filter(const float* __restrict__ x, const float* __restrict__ h,
                         float* __restrict__ F) {
    int a = blockIdx.x;
    int n = blockIdx.y;
    int k = threadIdx.x;
    __shared__ float sh[WDET];
    __shared__ float sc[WDET];
    sh[k] = h[k];
    sc[k] = x[(n * WDET + k) * NANG + a];
    __syncthreads();
    float acc = 0.0f;
#pragma unroll 4
    for (int j = 0; j < WDET; ++j) {
        int d = k - j;
        d = (d < 0) ? -d : d;
        acc = fmaf(sh[d], sc[j], acc);
    }
    F[(n * NANG + a) * WDET + k] = acc;
}

// ---------------------------------------------------------------------------
// Kernel 4: backprojection.
// For pixel (i,j): xg = unit[j], yg = unit[i] (bit-exact JAX linspace replica),
// iy(a) = xg*A[a] - yg*B[a] + 191.5 ; bilinear in detector axis with zero pad,
// accumulate over 180 angles; circle mask computed bit-exactly.
// block = (64,4), grid = (6, 96, 2).
// ---------------------------------------------------------------------------
__global__ void k_bp(const float* __restrict__ F, const float* __restrict__ AB,
                     float* __restrict__ out) {
    __shared__ float sA[NANG];
    __shared__ float sB[NANG];
    int tid = threadIdx.y * 64 + threadIdx.x;
    if (tid < NANG) {
        sA[tid] = AB[tid];
        sB[tid] = AB[tid + NANG];
    }
    __syncthreads();

    int j = blockIdx.x * 64 + threadIdx.x;
    int i = blockIdx.y * 4 + threadIdx.y;
    int n = blockIdx.z;

    const float delta = 2.0f / 383.0f;  // fl32(2/383), same as JAX linspace step
    // JAX linspace: out[i] = fl(i*delta) + (-1), endpoint forced to stop (=1.0)
    float xg = (j == 383) ? 1.0f : __fadd_rn(__fmul_rn((float)j, delta), -1.0f);
    float yg = (i == 383) ? 1.0f : __fadd_rn(__fmul_rn((float)i, delta), -1.0f);

    const float* Fn = F + n * NANG * WDET;
    float acc = 0.0f;
    for (int a = 0; a < NANG; ++a) {
        float iy = fmaf(xg, sA[a], 191.5f);
        iy = fmaf(-yg, sB[a], iy);
        float fy = floorf(iy);
        float wy = iy - fy;
        int r0 = (int)fy;
        int r1 = r0 + 1;
        float w0 = (r0 >= 0 && r0 <= 383) ? (1.0f - wy) : 0.0f;
        float w1 = (r1 >= 0 && r1 <= 383) ? wy : 0.0f;
        int r0c = min(max(r0, 0), 383);
        int r1c = min(max(r1, 0), 383);
        const float* Fa = Fn + a * WDET;
        acc = fmaf(w0, Fa[r0c], acc);
        acc = fmaf(w1, Fa[r1c], acc);
    }

    // circle mask: bit-exact replica of (xgrid**2 + ygrid**2) <= 1.0 in f32
    float xx = __fmul_rn(xg, xg);
    float yy = __fmul_rn(yg, yg);
    bool circ = __fadd_rn(xx, yy) <= 1.0f;

    out[n * (WDET * WDET) + i * WDET + j] = circ ? acc : 0.0f;
}

extern "C" void kernel_launch(void* const* d_in, const int* in_sizes, int n_in,
                              void* d_out, int out_size, void* d_ws, size_t ws_size,
                              hipStream_t stream) {
    const float* x = (const float*)d_in[0];
    float* out = (float*)d_out;

    float* F  = (float*)d_ws;          // 2*180*384 floats = 552960 B
    float* h  = F + 2 * NANG * WDET;   // 384 floats
    float* AB = h + WDET;              // 360 floats

    k_ramp<<<dim3(WDET), dim3(256), 0, stream>>>(h);
    k_trig<<<dim3(1), dim3(192), 0, stream>>>(AB);
    k_filter<<<dim3(NANG, 2), dim3(WDET), 0, stream>>>(x, h, F);
    k_bp<<<dim3(6, 96, 2), dim3(64, 4), 0, stream>>>(F, AB, out);
}

// Round 2
// 47.652 us; speedup vs baseline: 1.1447x; 1.1447x over previous
//
#include <hip/hip_runtime.h>
#include <math.h>

#define WDET 384
#define NANG 180
#define F2_FLOATS (2 * NANG * WDET)          // 138240 floats, layout [a][k][n]
#define F2_OFF    2                           // 2-float front pad (zeroed)
#define SHP_OFF   (F2_OFF + F2_FLOATS + 2)    // 2-float end pad (zeroed)
#define AB_OFF    (SHP_OFF + 768)

// ---------------------------------------------------------------------------
// Kernel 1: all tables.
//  blocks 0..383 : h[d] = (1/1024) sum_m filt[m] cos(2pi m d/1024), filt=2*min(m,1024-m)/1024,
//                  scaled by pi/360; stored as padded even table shp[383±d] (shp[767]=0).
//  block 384     : AB[a]=191.5*cos(rad_f32(a)), AB[180+a]=191.5*sin(...); zero F2 pads.
// ---------------------------------------------------------------------------
__global__ void k_tables(float* __restrict__ ws) {
    int b = blockIdx.x, t = threadIdx.x;
    if (b < 384) {
        int d = b;
        float local = 0.0f;
#pragma unroll
        for (int s = 0; s < 16; ++s) {
            int m = t + 64 * s;
            int mm = (m <= 512) ? m : (1024 - m);           // min(m, 1024-m)
            int tm = (m * d) & 1023;
            local += (float)mm * __cosf((float)tm * 6.135923151542565e-3f); // 2pi/1024
        }
        for (int off = 32; off > 0; off >>= 1) local += __shfl_down(local, off);
        if (t == 0) {
            float hd = local * (1.0f / 512.0f) * (1.0f / 1024.0f) * ((float)M_PI / 360.0f);
            ws[SHP_OFF + 383 + d] = hd;
            if (d) ws[SHP_OFF + 383 - d] = hd;
        }
    } else {
        for (int a = t; a < NANG; a += 64) {
            float radf = (float)a * (float)(M_PI / 180.0);   // f32 deg2rad, like jnp
            double c = cos((double)radf), s = sin((double)radf);
            ws[AB_OFF + a]        = (float)(191.5 * c);
            ws[AB_OFF + NANG + a] = (float)(191.5 * s);
        }
        if (t == 0) {
            ws[SHP_OFF + 767] = 0.0f;                         // unused pad element
            ws[0] = ws[1] = 0.0f;                             // F2 front pad (r0=-1)
            ws[F2_OFF + F2_FLOATS] = ws[F2_OFF + F2_FLOATS + 1] = 0.0f; // end pad (r1=384)
        }
    }
}

// ---------------------------------------------------------------------------
// Kernel 2: ramp filter as register-tiled correlation.
//  F[n,a,k] = sum_j shp[383+k-j] * x[n,0,j,a], written interleaved F2[(a*384+k)*2+n].
//  Block 192 threads = both n of one angle; 96 threads/col, 4 k-outputs/thread.
//  Inner: per 4 j's -> 3x ds_read_b128 (sc float4 + two aligned shp float4) + 16 FMA.
// ---------------------------------------------------------------------------
__global__ __launch_bounds__(192) void k_filter(const float* __restrict__ x,
                                                float* __restrict__ ws) {
    int a = blockIdx.x, tid = threadIdx.x;
    __shared__ __align__(16) float shp[768];
    __shared__ __align__(16) float sc[2][WDET];
    const float* __restrict__ shp_g = ws + SHP_OFF;
    for (int i = tid; i < 768; i += 192) shp[i] = shp_g[i];
    for (int i = tid; i < 768; i += 192) ((float*)sc)[i] = x[i * NANG + a]; // i = n*384+k
    __syncthreads();

    int n = tid / 96, t = tid % 96, k0 = 4 * t;
    float ax = 0.f, ay = 0.f, az = 0.f, aw = 0.f;
#pragma unroll 2
    for (int j = 0; j < WDET; j += 4) {
        float4 c = *(const float4*)&sc[n][j];
        int base = 380 + k0 - j;                 // base % 4 == 0 -> aligned b128
        float4 hA = *(const float4*)&shp[base];
        float4 hB = *(const float4*)&shp[base + 4];
        // w[t] = shp[base+t]; needed index = base + 3 + dk - dj
        ax = fmaf(hA.w, c.x, fmaf(hA.z, c.y, fmaf(hA.y, c.z, fmaf(hA.x, c.w, ax))));
        ay = fmaf(hB.x, c.x, fmaf(hA.w, c.y, fmaf(hA.z, c.z, fmaf(hA.y, c.w, ay))));
        az = fmaf(hB.y, c.x, fmaf(hB.x, c.y, fmaf(hA.w, c.z, fmaf(hA.z, c.w, az))));
        aw = fmaf(hB.z, c.x, fmaf(hB.y, c.y, fmaf(hB.x, c.z, fmaf(hA.w, c.w, aw))));
    }
    float* F2 = ws + F2_OFF;
    int kb = a * WDET + k0;
    F2[(kb + 0) * 2 + n] = ax;
    F2[(kb + 1) * 2 + n] = ay;
    F2[(kb + 2) * 2 + n] = az;
    F2[(kb + 3) * 2 + n] = aw;
}

// ---------------------------------------------------------------------------
// Kernel 3: backprojection, both batches per thread.
//  Inside circle iy is provably in [0,383] -> no per-corner bounds checks; single
//  clamp r0 to [-1,383] with zeroed pads covers rounding + outside-circle lanes
//  (masked at write). One float2 load per row fetches both batches.
// ---------------------------------------------------------------------------
__global__ __launch_bounds__(256) void k_bp(const float* __restrict__ ws,
                                            float* __restrict__ out) {
    const float2* __restrict__ f2 = (const float2*)(ws + F2_OFF);
    const float* __restrict__ AB = ws + AB_OFF;
    int j = blockIdx.x * 64 + threadIdx.x;
    int i = blockIdx.y * 4 + threadIdx.y;

    const float delta = 2.0f / 383.0f;   // fl32 linspace step, matches JAX
    float xg = (j == 383) ? 1.0f : __fadd_rn(__fmul_rn((float)j, delta), -1.0f);
    float yg = (i == 383) ? 1.0f : __fadd_rn(__fmul_rn((float)i, delta), -1.0f);
    bool circ = __fadd_rn(__fmul_rn(xg, xg), __fmul_rn(yg, yg)) <= 1.0f;

    int idx = i * WDET + j;
    if (__ballot(circ) == 0ULL) {        // whole wave outside the circle
        out[idx] = 0.0f;
        out[idx + WDET * WDET] = 0.0f;
        return;
    }

    float acc0 = 0.0f, acc1 = 0.0f;
    int rowbase = 0;
#pragma unroll 4
    for (int a = 0; a < NANG; ++a, rowbase += WDET) {
        float iy = fmaf(xg, AB[a], 191.5f);       // AB reads are uniform -> s_load
        iy = fmaf(-yg, AB[a + NANG], iy);
        float fy = floorf(iy);
        float wy = iy - fy;
        int r0 = (int)fy;
        r0 = min(max(r0, -1), 383);
        float2 p0 = f2[rowbase + r0];
        float2 p1 = f2[rowbase + r0 + 1];
        acc0 += fmaf(wy, p1.x - p0.x, p0.x);
        acc1 += fmaf(wy, p1.y - p0.y, p0.y);
    }
    out[idx] = circ ? acc0 : 0.0f;
    out[idx + WDET * WDET] = circ ? acc1 : 0.0f;
}

extern "C" void kernel_launch(void* const* d_in, const int* in_sizes, int n_in,
                              void* d_out, int out_size, void* d_ws, size_t ws_size,
                              hipStream_t stream) {
    const float* x = (const float*)d_in[0];
    float* out = (float*)d_out;
    float* ws = (float*)d_ws;

    k_tables<<<dim3(385), dim3(64), 0, stream>>>(ws);
    k_filter<<<dim3(NANG), dim3(192), 0, stream>>>(x, ws);
    k_bp<<<dim3(6, 96), dim3(64, 4), 0, stream>>>(ws, out);
}

// Round 3
// 34.441 us; speedup vs baseline: 1.5838x; 1.3836x over previous
//
#include <hip/hip_runtime.h>
#include <math.h>

#define WDET 384
#define NANG 180
#define F2_FLOATS (2 * NANG * WDET)   // layout [a][k][n], interleaved batches
#define F2_OFF    2                    // 2-float front pad (zeroed, covers r0=-1)

// ---------------------------------------------------------------------------
// Kernel 1: ramp filter, closed-form taps + even/odd split.
//  Closed form (exact DFT of reference's padded-FFT ramp, P=1024):
//    h[0]*s = 0.5*pi/360 ; h[even d] = 0 ; h[odd d]*s = -(pi/360)/(524288*sin^2(pi d/1024))
//  Even/odd split: F[2p]   = CEN*x[2p]   + sum_q G[q-p+192]*xo[q]
//                  F[2p+1] = CEN*x[2p+1] + sum_q G[q-p+191]*xe[q]
//  with G[192+m] = G[191-m] = h[2m+1]*s  (mirrored odd-tap table).
//  Block 192 threads = both batches of one angle; 4 outputs k0=4t per thread.
// ---------------------------------------------------------------------------
__global__ __launch_bounds__(192) void k_filter(const float* __restrict__ x,
                                                float* __restrict__ ws) {
    int a = blockIdx.x, tid = threadIdx.x;
    __shared__ __align__(16) float sG[388];
    __shared__ __align__(16) float sce[2][192];
    __shared__ __align__(16) float sco[2][192];

    // closed-form odd-tap table (385 entries, ~2 per thread)
    for (int i = tid; i < 385; i += 192) {
        int m = (i < 192) ? (191 - i) : (i - 192);
        int d = 2 * m + 1;
        float sd = __sinf((float)d * (float)(M_PI / 1024.0));
        float v = (float)(-(M_PI / 360.0) / 524288.0) / (sd * sd);
        sG[i] = (i == 384) ? 0.0f : v;
    }
    // stage this angle's detector column, deinterleaved into even/odd phases
    for (int i = tid; i < 768; i += 192) {          // i = n*384 + k
        float v = x[i * NANG + a];
        int n = (i >= 384) ? 1 : 0;
        int k = i - n * 384;
        if (k & 1) sco[n][k >> 1] = v;
        else       sce[n][k >> 1] = v;
    }
    __syncthreads();

    int n = (tid >= 96) ? 1 : 0;
    int t = tid - 96 * n;
    const float CEN = (float)(0.5 * M_PI / 360.0);
    float acc0 = CEN * sce[n][2 * t];
    float acc1 = CEN * sco[n][2 * t];
    float acc2 = CEN * sce[n][2 * t + 1];
    float acc3 = CEN * sco[n][2 * t + 1];
    int base0 = 191 - 2 * t;
#pragma unroll 4
    for (int q = 0; q < 192; q += 4) {
        float4 e = *(const float4*)&sce[n][q];
        float4 o = *(const float4*)&sco[n][q];
        int b = base0 + q;                           // odd -> b-1, b+1, b+3 even-aligned
        float2 gA = *(const float2*)&sG[b - 1];      // G[b-1], G[b]
        float2 gB = *(const float2*)&sG[b + 1];      // G[b+1], G[b+2]
        float2 gC = *(const float2*)&sG[b + 3];      // G[b+3], G[b+4]
        acc0 = fmaf(gB.x, o.x, fmaf(gB.y, o.y, fmaf(gC.x, o.z, fmaf(gC.y, o.w, acc0))));
        acc1 = fmaf(gA.y, e.x, fmaf(gB.x, e.y, fmaf(gB.y, e.z, fmaf(gC.x, e.w, acc1))));
        acc2 = fmaf(gA.y, o.x, fmaf(gB.x, o.y, fmaf(gB.y, o.z, fmaf(gC.x, o.w, acc2))));
        acc3 = fmaf(gA.x, e.x, fmaf(gA.y, e.y, fmaf(gB.x, e.z, fmaf(gB.y, e.w, acc3))));
    }
    float* F2 = ws + F2_OFF;
    int kb = a * WDET + 4 * t;
    F2[(kb + 0) * 2 + n] = acc0;
    F2[(kb + 1) * 2 + n] = acc1;
    F2[(kb + 2) * 2 + n] = acc2;
    F2[(kb + 3) * 2 + n] = acc3;
    if (a == 0 && tid == 0) {                        // zero pads for r0 in {-1, 383}
        ws[0] = ws[1] = 0.0f;
        ws[F2_OFF + F2_FLOATS] = 0.0f;
        ws[F2_OFF + F2_FLOATS + 1] = 0.0f;
    }
}

// ---------------------------------------------------------------------------
// Kernel 2: backprojection, both batches per thread, in-block trig tables.
// ---------------------------------------------------------------------------
__global__ __launch_bounds__(256) void k_bp(const float* __restrict__ ws,
                                            float* __restrict__ out) {
    __shared__ float sA[NANG], sB[NANG];
    int tid = threadIdx.y * 64 + threadIdx.x;
    if (tid < NANG) {
        float rad = (float)tid * (float)(M_PI / 180.0);  // f32 deg2rad, like jnp
        float s, c;
        __sincosf(rad, &s, &c);
        sA[tid] = 191.5f * c;
        sB[tid] = 191.5f * s;
    }
    __syncthreads();

    const float2* __restrict__ f2 = (const float2*)(ws + F2_OFF);
    int j = blockIdx.x * 64 + threadIdx.x;
    int i = blockIdx.y * 4 + threadIdx.y;

    const float delta = 2.0f / 383.0f;   // fl32 linspace step, matches JAX
    float xg = (j == 383) ? 1.0f : __fadd_rn(__fmul_rn((float)j, delta), -1.0f);
    float yg = (i == 383) ? 1.0f : __fadd_rn(__fmul_rn((float)i, delta), -1.0f);
    bool circ = __fadd_rn(__fmul_rn(xg, xg), __fmul_rn(yg, yg)) <= 1.0f;

    int idx = i * WDET + j;
    if (__ballot(circ) == 0ULL) {        // whole wave outside the circle
        out[idx] = 0.0f;
        out[idx + WDET * WDET] = 0.0f;
        return;
    }

    float acc0 = 0.0f, acc1 = 0.0f;
    int rowbase = 0;
#pragma unroll 4
    for (int a = 0; a < NANG; ++a, rowbase += WDET) {
        float iy = fmaf(xg, sA[a], 191.5f);
        iy = fmaf(-yg, sB[a], iy);
        float fy = floorf(iy);
        float wy = iy - fy;
        int r0 = (int)fy;
        r0 = min(max(r0, -1), 383);
        float2 p0 = f2[rowbase + r0];
        float2 p1 = f2[rowbase + r0 + 1];
        acc0 += fmaf(wy, p1.x - p0.x, p0.x);
        acc1 += fmaf(wy, p1.y - p0.y, p0.y);
    }
    out[idx] = circ ? acc0 : 0.0f;
    out[idx + WDET * WDET] = circ ? acc1 : 0.0f;
}

extern "C" void kernel_launch(void* const* d_in, const int* in_sizes, int n_in,
                              void* d_out, int out_size, void* d_ws, size_t ws_size,
                              hipStream_t stream) {
    const float* x = (const float*)d_in[0];
    float* out = (float*)d_out;
    float* ws = (float*)d_ws;

    k_filter<<<dim3(NANG), dim3(192), 0, stream>>>(x, ws);
    k_bp<<<dim3(6, 96), dim3(64, 4), 0, stream>>>(ws, out);
}